// Round 1
// baseline (58.842 us; speedup 1.0000x reference)
//
#include <hip/hip_runtime.h>

#define T_STEPS 128
#define H 512
#define W 512
#define PLANE (H * W)

// One thread per pixel. Each thread keeps LIF state (v, i) in registers and
// loops over all 128 timesteps, computing the 5-tap cross conv on the fly.
// Border handling: clamp the neighbor address (always a valid load) and zero
// the weight — exact, since acc + 0*x == acc, matching zero padding.
__global__ __launch_bounds__(256) void lif_conv_scan(const float* __restrict__ x,
                                                     const float* __restrict__ k,
                                                     float* __restrict__ out) {
    const int w = blockIdx.x * 64 + threadIdx.x;   // 0..511
    const int h = blockIdx.y * 4 + threadIdx.y;    // 0..511
    const int idx = h * W + w;

    // conv weights from the kernel input (cross taps; corners are 0.0)
    const float kU = k[1], kL = k[3], kC = k[4], kR = k[5], kD = k[7];

    const int offU = (h > 0)     ? idx - W : idx;
    const int offD = (h < H - 1) ? idx + W : idx;
    const int offL = (w > 0)     ? idx - 1 : idx;
    const int offR = (w < W - 1) ? idx + 1 : idx;
    const float wU = (h > 0)     ? kU : 0.0f;
    const float wD = (h < H - 1) ? kD : 0.0f;
    const float wL = (w > 0)     ? kL : 0.0f;
    const float wR = (w < W - 1) ? kR : 0.0f;

    float v = 0.0f;
    float cur = 0.0f;
    const float* xp = x;
    float* op = out + idx;

    #pragma unroll 4
    for (int t = 0; t < T_STEPS; ++t) {
        // 5-tap cross conv, row-major accumulation order
        const float xu = xp[offU];
        const float xl = xp[offL];
        const float xc = xp[idx];
        const float xr = xp[offR];
        const float xd = xp[offD];
        float c = wU * xu;
        c += wL * xl;
        c += kC * xc;
        c += wR * xr;
        c += wD * xd;

        // LIF step — mirror reference op order exactly
        const float v_dec = v + 0.2f * ((0.0f - v) + cur);
        const float i_dec = cur * 0.8f;
        const bool spike = (v_dec - 1.0f) > 0.0f;
        const float z = spike ? 1.0f : 0.0f;
        v = spike ? 0.0f : v_dec;      // exact: (1-z)*v_dec + z*0
        cur = i_dec + c;

        __builtin_nontemporal_store(z, op);  // don't let output evict x from L3
        xp += PLANE;
        op += PLANE;
    }
}

extern "C" void kernel_launch(void* const* d_in, const int* in_sizes, int n_in,
                              void* d_out, int out_size, void* d_ws, size_t ws_size,
                              hipStream_t stream) {
    const float* x = (const float*)d_in[0];
    const float* k = (const float*)d_in[1];
    float* out = (float*)d_out;

    dim3 block(64, 4);
    dim3 grid(W / 64, H / 4);   // 8 x 128 = 1024 blocks
    lif_conv_scan<<<grid, block, 0, stream>>>(x, k, out);
}

// Round 3
// 57.135 us; speedup vs baseline: 1.0299x; 1.0299x over previous
//
#include <hip/hip_runtime.h>

#define T_STEPS 128
#define H 512
#define W 512
#define PLANE (H * W)

typedef float f2 __attribute__((ext_vector_type(2)));  // native vector: nontemporal-store OK

// Two pixels (w0, w0+1) per thread via float2-width loads. LIF state in
// registers across the 128-step scan; 5-tap cross conv computed on the fly
// from 8B loads (center/up/down) + 2 scalar edge loads.
// Software pipeline: issue t+1's loads before computing t's LIF update.
__global__ __launch_bounds__(256) void lif_conv_scan(const float* __restrict__ x,
                                                     const float* __restrict__ k,
                                                     float* __restrict__ out) {
    const int wpair = blockIdx.x * 64 + threadIdx.x;   // 0..255
    const int w0 = wpair * 2;                          // even pixel column
    const int h = blockIdx.y * 4 + threadIdx.y;        // 0..511
    const int idx = h * W + w0;

    const float kU = k[1], kL = k[3], kC = k[4], kR = k[5], kD = k[7];

    // clamped neighbor offsets + zeroed weights at borders (exact: acc + 0*x == acc)
    const int offU = (h > 0)      ? idx - W : idx;
    const int offD = (h < H - 1)  ? idx + W : idx;
    const float wU = (h > 0)      ? kU : 0.0f;
    const float wD = (h < H - 1)  ? kD : 0.0f;
    const int offL = (w0 > 0)     ? idx - 1 : idx;     // left neighbor of p0
    const int offR = (w0 < W - 2) ? idx + 2 : idx;     // right neighbor of p1
    const float wL = (w0 > 0)     ? kL : 0.0f;
    const float wR = (w0 < W - 2) ? kR : 0.0f;

    float v0 = 0.0f, v1 = 0.0f, i0 = 0.0f, i1 = 0.0f;

    const float* xp = x;
    float* op = out + idx;

    // preload t = 0
    f2 c = *(const f2*)(xp + idx);
    f2 u = *(const f2*)(xp + offU);
    f2 d = *(const f2*)(xp + offD);
    float lf = xp[offL];
    float rt = xp[offR];

    #pragma unroll 4
    for (int t = 0; t < T_STEPS; ++t) {
        // issue next timestep's loads early (clamp last iter to a valid plane;
        // those loads are L1 hits and their values are discarded)
        const float* xn = (t < T_STEPS - 1) ? (xp + PLANE) : xp;
        const f2 nc = *(const f2*)(xn + idx);
        const f2 nu = *(const f2*)(xn + offU);
        const f2 nd = *(const f2*)(xn + offD);
        const float nlf = xn[offL];
        const float nrt = xn[offR];

        // conv, same accumulation order as the verified round-0 kernel
        float c0 = wU * u.x;
        c0 += wL * lf;
        c0 += kC * c.x;
        c0 += kR * c.y;      // p0's right neighbor always exists
        c0 += wD * d.x;

        float c1 = wU * u.y;
        c1 += kL * c.x;      // p1's left neighbor always exists
        c1 += kC * c.y;
        c1 += wR * rt;
        c1 += wD * d.y;

        // LIF step, pixel 0
        const float vd0 = v0 + 0.2f * (i0 - v0);
        const bool s0 = (vd0 - 1.0f) > 0.0f;
        const float z0 = s0 ? 1.0f : 0.0f;
        v0 = s0 ? 0.0f : vd0;
        i0 = i0 * 0.8f + c0;

        // LIF step, pixel 1
        const float vd1 = v1 + 0.2f * (i1 - v1);
        const bool s1 = (vd1 - 1.0f) > 0.0f;
        const float z1 = s1 ? 1.0f : 0.0f;
        v1 = s1 ? 0.0f : vd1;
        i1 = i1 * 0.8f + c1;

        f2 z;
        z.x = z0;
        z.y = z1;
        __builtin_nontemporal_store(z, (f2*)op);

        // rotate pipeline
        c = nc; u = nu; d = nd; lf = nlf; rt = nrt;
        xp = xn;
        op += PLANE;
    }
}

extern "C" void kernel_launch(void* const* d_in, const int* in_sizes, int n_in,
                              void* d_out, int out_size, void* d_ws, size_t ws_size,
                              hipStream_t stream) {
    const float* x = (const float*)d_in[0];
    const float* k = (const float*)d_in[1];
    float* out = (float*)d_out;

    dim3 block(64, 4);
    dim3 grid(W / 128, H / 4);   // 4 x 128 = 512 blocks, 2 per CU
    lif_conv_scan<<<grid, block, 0, stream>>>(x, k, out);
}